// Round 2
// baseline (203.837 us; speedup 1.0000x reference)
//
#include <hip/hip_runtime.h>

// ZGate, D=4, S=1, INDEX=(0,2,5,8), L=10, N=4^10=1048576, B=16.
// phase(n) = i^t, t = ((n>>18)+(n>>14)+(n>>8)+(n>>2)) & 3   (bit-pair digits of n)
// Input x: [2, N, B] float32 planar (re plane then im plane).
// Output: branch on out_size —
//   out_size == N*B   : harness coerced complex64 -> float32 (real part only)
//   out_size == 2*N*B : interleaved (re,im) float pairs (complex64 .view(f32))

#define NSTATES (1u << 20)   // 4^10
#define BATCH   16u

__device__ __forceinline__ void phase_for(unsigned n, float& c, float& s) {
    unsigned t = ((n >> 18) + (n >> 14) + (n >> 8) + (n >> 2)) & 3u;
    // i^t: (c, s) = (Re, Im)
    c = (t & 1u) ? 0.0f : ((t & 2u) ? -1.0f : 1.0f);
    s = (t & 1u) ? ((t & 2u) ? -1.0f : 1.0f) : 0.0f;
}

// Real-part-only output: out[n,b] = c*re - s*im, N*B floats.
__global__ __launch_bounds__(256) void zgate_real(const float* __restrict__ x,
                                                  float* __restrict__ out) {
    unsigned tid = blockIdx.x * blockDim.x + threadIdx.x;   // [0, N*B/4)
    unsigned n = tid >> 2;                                  // 4 float4-groups per n

    float4 re = reinterpret_cast<const float4*>(x)[tid];
    float4 im = reinterpret_cast<const float4*>(x + (size_t)NSTATES * BATCH)[tid];

    float c, s;
    phase_for(n, c, s);

    float4 o;
    o.x = c * re.x - s * im.x;
    o.y = c * re.y - s * im.y;
    o.z = c * re.z - s * im.z;
    o.w = c * re.w - s * im.w;
    reinterpret_cast<float4*>(out)[tid] = o;
}

// Interleaved complex output: out[(n*B+b)*2 + {0,1}] = (re', im'), 2*N*B floats.
__global__ __launch_bounds__(256) void zgate_cplx(const float* __restrict__ x,
                                                  float* __restrict__ out) {
    unsigned tid = blockIdx.x * blockDim.x + threadIdx.x;   // [0, N*B/4)
    unsigned n = tid >> 2;

    float4 re = reinterpret_cast<const float4*>(x)[tid];
    float4 im = reinterpret_cast<const float4*>(x + (size_t)NSTATES * BATCH)[tid];

    float c, s;
    phase_for(n, c, s);

    float4 o0, o1;
    o0.x = c * re.x - s * im.x;  o0.y = s * re.x + c * im.x;
    o0.z = c * re.y - s * im.y;  o0.w = s * re.y + c * im.y;
    o1.x = c * re.z - s * im.z;  o1.y = s * re.z + c * im.z;
    o1.z = c * re.w - s * im.w;  o1.w = s * re.w + c * im.w;

    float4* out4 = reinterpret_cast<float4*>(out) + (size_t)tid * 2;
    out4[0] = o0;
    out4[1] = o1;
}

extern "C" void kernel_launch(void* const* d_in, const int* in_sizes, int n_in,
                              void* d_out, int out_size, void* d_ws, size_t ws_size,
                              hipStream_t stream) {
    const float* x = (const float*)d_in[0];
    float* out = (float*)d_out;

    const unsigned NB = NSTATES * BATCH;          // 16,777,216
    const unsigned total_threads = NB / 4;        // 4,194,304
    dim3 block(256);
    dim3 grid(total_threads / 256);               // 16384 blocks

    if ((unsigned)out_size >= 2u * NB) {
        zgate_cplx<<<grid, block, 0, stream>>>(x, out);
    } else {
        zgate_real<<<grid, block, 0, stream>>>(x, out);
    }
}